// Round 8
// baseline (7090.664 us; speedup 1.0000x reference)
//
#include <hip/hip_runtime.h>

// LSTM S=512,B=64,I=256,H=512 (f32 buffers).
// R8: R5/R7 both 2.6ms -> per-step cost is the serialized sync chain, not
// work. Fix: per-producer chunk pipeline. Each wave: lane-parallel flag wait
// (lane i polls producer wg+1+i), then streams 15 remote K-chunks DIRECTLY
// from hb into MFMA B-frags (2 coalesced u64 coherent loads per frag, zero
// amplification), own chunk from the 4KB hst LDS buffer. No HL staging tier
// (-1 barrier, -bank conflicts). Tail after last flag ~= 1 chunk + pointwise
// + publish. Flags 64B-strided. Double accumulator halves MFMA dep chain.
// Sync: proven fence-free relaxed agent-scope protocol (R5).

#define SS 512
#define BB 64
#define II 256
#define HH 512
#define NWG 16
#define GROW 2048
#define TBN  (SS*BB)

typedef unsigned int u32;
typedef unsigned short u16;
typedef unsigned long long u64;
typedef _Float16 __attribute__((ext_vector_type(8))) h16x8;
typedef __attribute__((ext_vector_type(2))) float f32x2;
typedef __attribute__((ext_vector_type(4))) float f32x4;
typedef __attribute__((ext_vector_type(16))) float f32x16;
typedef u32 __attribute__((ext_vector_type(4))) u32x4;
typedef u32 __attribute__((ext_vector_type(2))) u32x2;

// ---------------- XP-path ws layout ----------------
#define A2_DW   (NWG * 4 * 32 * 256)          // 524288 dwords = 2 MB (h A-frags)
#define WXA_DW  (64 * 16 * 256)               // 262144 dwords = 1 MB (x A-frags)
#define XA2_OFF  0
#define XWXA_OFF ((size_t)A2_DW * 4)                    // 2,097,152
#define XBS_OFF  (XWXA_OFF + (size_t)WXA_DW * 4)        // 3,145,728 (bsum 8 KB)
#define XHB_OFF  (XBS_OFF + 8192)                       // 3,153,920 (hb 128 KB)
#define XFL_OFF  (XHB_OFF + 2 * (size_t)BB * HH * 2)    // 3,284,992 (flags 1 KB)
#define XXP_OFF  ((size_t)4 * 1024 * 1024)              // 4,194,304
#define XP_BYTES ((size_t)GROW * TBN * 2)               // 134,217,728
#define WS_XP    (XXP_OFF + XP_BYTES)                   // 138,412,032

// ---------------- R5-fallback ws layout ----------------
#define A_DWORDS (32 * 2 * 2 * 24 * 64 * 4)           // 786432
#define HB_OFF   ((size_t)A_DWORDS * 4)               // 3,145,728
#define FL_OFF   (HB_OFF + 2 * (size_t)BB * HH * 2)   // +131,072
#define WS_NEED  (FL_OFF + 4096)

__device__ __forceinline__ u32 pk2h(float a, float b) {
    union { _Float16 h[2]; u32 u; } v;
    v.h[0] = (_Float16)a; v.h[1] = (_Float16)b; return v.u;
}
__device__ __forceinline__ u16 f2h(float a) {
    union { _Float16 h; u16 u; } v; v.h = (_Float16)a; return v.u;
}
__device__ __forceinline__ float h2f(u16 u) {
    union { u16 u; _Float16 h; } v; v.u = u; return (float)v.h;
}
__device__ __forceinline__ float sigf(float v)  { return 1.0f / (1.0f + __expf(-v)); }
__device__ __forceinline__ float tanhf_(float v){ return 1.0f - 2.0f / (1.0f + __expf(2.0f * v)); }

// relaxed agent-scope (coherent-at-L3, no cache-maintenance fences)
__device__ __forceinline__ void st_u32_coh(u32* p, u32 v) {
    __hip_atomic_store(p, v, __ATOMIC_RELAXED, __HIP_MEMORY_SCOPE_AGENT);
}
__device__ __forceinline__ void st_u64_coh(u64* p, u64 v) {
    __hip_atomic_store(p, v, __ATOMIC_RELAXED, __HIP_MEMORY_SCOPE_AGENT);
}
__device__ __forceinline__ void st_i32_coh(int* p, int v) {
    __hip_atomic_store(p, v, __ATOMIC_RELAXED, __HIP_MEMORY_SCOPE_AGENT);
}
__device__ __forceinline__ int ld_i32_coh(const int* p) {
    return __hip_atomic_load(p, __ATOMIC_RELAXED, __HIP_MEMORY_SCOPE_AGENT);
}
__device__ __forceinline__ u64 ld_u64_coh(const u64* p) {
    return __hip_atomic_load(p, __ATOMIC_RELAXED, __HIP_MEMORY_SCOPE_AGENT);
}

// ===================================================================
// XP path
// ===================================================================

__global__ __launch_bounds__(256) void xprep_pack(
    const float* __restrict__ Wfi, const float* __restrict__ Wfh,
    const float* __restrict__ Wii, const float* __restrict__ Wih,
    const float* __restrict__ Wci, const float* __restrict__ Wch,
    const float* __restrict__ Woi, const float* __restrict__ Woh,
    const float* __restrict__ bfi, const float* __restrict__ bfh,
    const float* __restrict__ bii, const float* __restrict__ bih,
    const float* __restrict__ bci, const float* __restrict__ bch,
    const float* __restrict__ boi, const float* __restrict__ boh,
    u32* __restrict__ A2, u32* __restrict__ WXA, float* __restrict__ bsum)
{
    int tid = blockIdx.x * 256 + threadIdx.x;
    if (tid < A2_DW) {
        int d = tid & 3, l = (tid >> 2) & 63, kt = (tid >> 8) & 31;
        int mt = (tid >> 13) & 3, wg = tid >> 15;
        int r = l & 31, g = r & 3, ml = r >> 2;
        int j = wg * 32 + mt * 8 + ml;
        int k = kt * 16 + (l >> 5) * 8 + d * 2;
        const float* Wh = (g == 0) ? Wfh : (g == 1) ? Wih : (g == 2) ? Wch : Woh;
        A2[tid] = pk2h(Wh[j * HH + k], Wh[j * HH + k + 1]);
    } else if (tid < A2_DW + WXA_DW) {
        int t2 = tid - A2_DW;
        int d = t2 & 3, l = (t2 >> 2) & 63, kt = (t2 >> 8) & 15, gt = t2 >> 12;
        int r = l & 31, g = r & 3;
        int j = gt * 8 + (r >> 2);
        int k = kt * 16 + (l >> 5) * 8 + d * 2;
        const float* Wi = (g == 0) ? Wfi : (g == 1) ? Wii : (g == 2) ? Wci : Woi;
        WXA[t2] = pk2h(Wi[j * II + k], Wi[j * II + k + 1]);
    } else if (tid < A2_DW + WXA_DW + GROW) {
        int grow = tid - A2_DW - WXA_DW;
        int r = grow & 31, gt = grow >> 5;
        int g = r & 3, j = gt * 8 + (r >> 2);
        const float* bi = (g == 0) ? bfi : (g == 1) ? bii : (g == 2) ? bci : boi;
        const float* bh = (g == 0) ? bfh : (g == 1) ? bih : (g == 2) ? bch : boh;
        bsum[grow] = bi[j] + bh[j];
    }
}

__global__ __launch_bounds__(256) void xprep_hb(
    const float* __restrict__ h0, u16* __restrict__ hb, int* __restrict__ flags)
{
    int tid = blockIdx.x * 256 + threadIdx.x;   // < 32768
    if (tid < BB * HH) {
        int b = tid >> 9, j = tid & 511;
        hb[(j >> 3) * 512 + b * 8 + (j & 7)] = f2h(h0[tid]);
    }
    if (tid < NWG) flags[tid * 16] = 0;   // 64B-strided flags
}

// xproj: XPq[(j*512 + t)*64 + b] = u64 of 4 f16 gates {f,i,c,o} of unit j.
__global__ __launch_bounds__(512, 1) void xproj(
    const float* __restrict__ x, const u32* __restrict__ WXA,
    const float* __restrict__ bsum, u64* __restrict__ XPq)
{
    const int wgid = blockIdx.x;
    const int tid = threadIdx.x, lane = tid & 63, w = tid >> 6;
    const int TB0 = wgid * 128;
    __shared__ __align__(16) u32 XB[32 * 128 * 4];

    #pragma unroll
    for (int it = 0; it < 16; ++it) {
        int c = it * 512 + tid;
        int m = c >> 6, ck = c & 63;
        f32x4 v = *(const f32x4*)(x + (size_t)(TB0 + m) * II + ck * 4);
        u32x2 p; p.x = pk2h(v.x, v.y); p.y = pk2h(v.z, v.w);
        *(u32x2*)(XB + ((ck >> 1) * 128 + m) * 4 + (ck & 1) * 2) = p;
    }
    __syncthreads();

    const int gtw = w & 3, nh = w >> 2;
    const int khi = lane >> 5;
    for (int nt = 0; nt < 2; ++nt) {
        const int col = nh * 64 + nt * 32 + (lane & 31);
        const int tb = TB0 + col;
        const int t_ = tb >> 6, b_ = tb & 63;
        h16x8 bfr[16];
        #pragma unroll
        for (int kt = 0; kt < 16; ++kt)
            bfr[kt] = *(const h16x8*)(XB + ((kt * 2 + khi) * 128 + col) * 4);
        for (int gti = 0; gti < 16; ++gti) {
            const int gt = gtw * 16 + gti;
            f32x16 acc;
            #pragma unroll
            for (int rg = 0; rg < 16; ++rg)
                acc[rg] = bsum[gt * 32 + (rg & 3) + 8 * (rg >> 2) + 4 * khi];
            const u32* ap = WXA + (size_t)(gt * 16) * 256 + lane * 4;
            #pragma unroll
            for (int kt = 0; kt < 16; ++kt) {
                h16x8 af = *(const h16x8*)(ap + kt * 256);
                acc = __builtin_amdgcn_mfma_f32_32x32x16_f16(af, bfr[kt], acc, 0, 0, 0);
            }
            #pragma unroll
            for (int q = 0; q < 4; ++q) {
                int j = gt * 8 + 2 * q + khi;
                union { u16 s[4]; u64 u; } pk;
                pk.s[0] = f2h(acc[4 * q + 0]);
                pk.s[1] = f2h(acc[4 * q + 1]);
                pk.s[2] = f2h(acc[4 * q + 2]);
                pk.s[3] = f2h(acc[4 * q + 3]);
                XPq[((size_t)j * 512 + t_) * 64 + b_] = pk.u;
            }
        }
    }
}

// recurrent: per-producer chunk pipeline, direct hb->B-frag coherent loads.
__global__ __launch_bounds__(512) void lstm_rec(
    const float* __restrict__ c0,
    const u32* __restrict__ A2, u16* __restrict__ hb, int* __restrict__ flags,
    const u64* __restrict__ XPq, float* __restrict__ out)
{
    const int wg = blockIdx.x, tid = threadIdx.x, lane = tid & 63, w = tid >> 6;
    const int mt = w & 3, nt2 = w >> 2;
    const int khi = lane >> 5;
    const int b = nt2 * 32 + (lane & 31);

    __shared__ __align__(16) u16 hst[2048];   // 4 KB: [mt][b][e8] of this WG's slice
    u64* hst64 = (u64*)hst;
    u64* hb64  = (u64*)hb;

    // A-fragments resident in VGPRs (32 x 16B = 128 VGPRs)
    h16x8 afr[32];
    {
        const u32* ab = A2 + (size_t)(wg * 4 + mt) * (32 * 256) + lane * 4;
        #pragma unroll
        for (int kt = 0; kt < 32; ++kt) afr[kt] = *(const h16x8*)(ab + kt * 256);
    }

    // c-state: lane owns batch b, units j = wg*32 + mt*8 + 2q + khi
    float cst[4];
    #pragma unroll
    for (int q = 0; q < 4; ++q)
        cst[q] = c0[b * HH + wg * 32 + mt * 8 + 2 * q + khi];

    // prologue: stage own h0 slice into hst (same addressing as publish)
    hst64[tid] = ld_u64_coh(hb64 + wg * 512 + tid);
    __syncthreads();

    for (int t = 0; t < SS; ++t) {
        const u64* hbase = hb64 + (size_t)(t & 1) * 8192;

        // XP prefetch: one u64 (4 gates) per unit, coalesced plain loads
        u64 xq[4];
        #pragma unroll
        for (int q = 0; q < 4; ++q) {
            int j = wg * 32 + mt * 8 + 2 * q + khi;
            xq[q] = XPq[((size_t)j * 512 + t) * 64 + b];
        }

        // own chunk (producer wg) from hst LDS — no global read, no flag
        f32x16 acc0, acc1;
        #pragma unroll
        for (int rg = 0; rg < 16; ++rg) { acc0[rg] = 0.0f; acc1[rg] = 0.0f; }
        {
            h16x8 bf0 = *(const h16x8*)(hst + (khi) * 512 + b * 8);
            h16x8 bf1 = *(const h16x8*)(hst + (2 + khi) * 512 + b * 8);
            acc0 = __builtin_amdgcn_mfma_f32_32x32x16_f16(afr[2 * wg],     bf0, acc0, 0, 0, 0);
            acc1 = __builtin_amdgcn_mfma_f32_32x32x16_f16(afr[2 * wg + 1], bf1, acc1, 0, 0, 0);
        }

        // lane-parallel wait: lane i polls producer (wg+1+i)'s flag
        if (lane < NWG - 1) {
            const int p = (wg + 1 + lane) & (NWG - 1);
            while (ld_i32_coh(&flags[p * 16]) < t) {}
        }
        asm volatile("" ::: "memory");

        // stream 15 remote chunks: 2 frags each, direct coherent u64 loads
        #pragma unroll
        for (int i = 1; i < NWG; ++i) {
            const int p = (wg + i) & (NWG - 1);
            union { u64 q[2]; h16x8 h; } u0, u1;
            {
                const u64* bp = hbase + (size_t)(4 * p + khi) * 128 + b * 2;
                u0.q[0] = ld_u64_coh(bp); u0.q[1] = ld_u64_coh(bp + 1);
            }
            {
                const u64* bp = hbase + (size_t)(4 * p + 2 + khi) * 128 + b * 2;
                u1.q[0] = ld_u64_coh(bp); u1.q[1] = ld_u64_coh(bp + 1);
            }
            acc0 = __builtin_amdgcn_mfma_f32_32x32x16_f16(afr[2 * p],     u0.h, acc0, 0, 0, 0);
            acc1 = __builtin_amdgcn_mfma_f32_32x32x16_f16(afr[2 * p + 1], u1.h, acc1, 0, 0, 0);
        }

        __syncthreads();   // #1: all waves done reading hst (own chunk)

        // in-register pointwise; write h slice into hst
        float hvv[4];
        #pragma unroll
        for (int q = 0; q < 4; ++q) {
            union { u64 u; u16 s[4]; } xu; xu.u = xq[q];
            float af = acc0[4 * q + 0] + acc1[4 * q + 0] + h2f(xu.s[0]);
            float ai = acc0[4 * q + 1] + acc1[4 * q + 1] + h2f(xu.s[1]);
            float ac = acc0[4 * q + 2] + acc1[4 * q + 2] + h2f(xu.s[2]);
            float ao = acc0[4 * q + 3] + acc1[4 * q + 3] + h2f(xu.s[3]);
            float cn = cst[q] * sigf(af) + sigf(ai) * tanhf_(ac);
            cst[q] = cn;
            float hv = sigf(ao) * tanhf_(cn);
            hvv[q] = hv;
            hst[mt * 512 + b * 8 + 2 * q + khi] = f2h(hv);
        }

        if (t < SS - 1) {
            __syncthreads();   // #2: hst complete
            // publish: 512 consecutive u64 coherent stores (fully coalesced)
            u64 pk = hst64[tid];
            st_u64_coh(hb64 + (size_t)((t + 1) & 1) * 8192 + wg * 512 + tid, pk);
            __syncthreads();   // #3: per-wave vmcnt(0) drain -> stores visible
            if (tid == 0) st_i32_coh(&flags[wg * 16], t + 1);
        }

        // out stores after flag publish (drain hides in next step)
        #pragma unroll
        for (int q = 0; q < 4; ++q) {
            int j = wg * 32 + mt * 8 + 2 * q + khi;
            out[((size_t)t * BB + b) * HH + j] = hvv[q];
        }
        if (t == SS - 1) {
            #pragma unroll
            for (int q = 0; q < 4; ++q) {
                int j = wg * 32 + mt * 8 + 2 * q + khi;
                out[(size_t)SS * BB * HH + b * HH + j] = hvv[q];
                out[(size_t)SS * BB * HH + BB * HH + b * HH + j] = cst[q];
            }
        }
    }
}

// ===================================================================
// R5 fallback path (proven 2.63 ms) — verbatim
// ===================================================================
__global__ __launch_bounds__(256) void prep_A(
    const float* __restrict__ Wfi, const float* __restrict__ Wfh,
    const float* __restrict__ Wii, const float* __restrict__ Wih,
    const float* __restrict__ Wci, const float* __restrict__ Wch,
    const float* __restrict__ Woi, const float* __restrict__ Woh,
    u32* __restrict__ A)
{
    int tid = blockIdx.x * 256 + threadIdx.x;
    int wg = tid / 24576;  int r = tid - wg * 24576;
    int mt = r / 12288;    r -= mt * 12288;
    int ks = r / 6144;     r -= ks * 6144;
    int kt = r / 256;      r -= kt * 256;
    int l  = r >> 2;       int d = r & 3;

    int row = mt * 32 + (l & 31);
    int g   = row >> 4;
    int j   = wg * 16 + (row & 15);
    int k   = ks * 384 + kt * 16 + (l >> 5) * 8 + d * 2;

    const float* Wi = (g == 0) ? Wfi : (g == 1) ? Wii : (g == 2) ? Wci : Woi;
    const float* Wh = (g == 0) ? Wfh : (g == 1) ? Wih : (g == 2) ? Wch : Woh;
    float w0, w1;
    if (k < II) { w0 = Wi[j * II + k];        w1 = Wi[j * II + k + 1]; }
    else        { int kk = k - II; w0 = Wh[j * HH + kk]; w1 = Wh[j * HH + kk + 1]; }
    A[tid] = pk2h(w0, w1);
}

__global__ __launch_bounds__(256) void prep_misc(
    const float* __restrict__ h0, u16* __restrict__ hb, int* __restrict__ flags)
{
    int tid = blockIdx.x * 256 + threadIdx.x;
    if (tid < BB * HH) {
        int b = tid >> 9, j = tid & 511;
        hb[(j >> 3) * 512 + b * 8 + (j & 7)] = f2h(h0[tid]);
    }
    if (tid < 32) flags[tid * 32] = 0;
}

__global__ __launch_bounds__(512, 1) void lstm_mfma(
    const float* __restrict__ x,  const float* __restrict__ c0,
    const float* __restrict__ bfi, const float* __restrict__ bfh,
    const float* __restrict__ bii, const float* __restrict__ bih,
    const float* __restrict__ bci, const float* __restrict__ bch,
    const float* __restrict__ boi, const float* __restrict__ boh,
    const u32* __restrict__ A, u16* __restrict__ hb, int* __restrict__ flags,
    float* __restrict__ out)
{
    const int wg   = blockIdx.x;
    const int tid  = threadIdx.x;
    const int lane = tid & 63;
    const int w    = tid >> 6;
    const int mt   = w & 1;
    const int nt2  = (w >> 1) & 1;
    const int ks   = w >> 2;
    const int khi  = lane >> 5;
    const int nb   = nt2 * 32 + (lane & 31);

    __shared__ __align__(16) u16 BS[8192 * 8];
    char* BSc = (char*)BS;

    h16x8 afr[24];
    {
        const u32* ab = A + ((wg * 2 + mt) * 2 + ks) * (24 * 256) + lane * 4;
        #pragma unroll
        for (int kt = 0; kt < 24; ++kt)
            afr[kt] = *(const h16x8*)(ab + kt * 256);
    }

    f32x16 acc_init;
    #pragma unroll
    for (int rg = 0; rg < 16; ++rg) {
        int row = mt * 32 + (rg & 3) + 8 * (rg >> 2) + 4 * khi;
        float bv = 0.0f;
        if (ks == 0) {
            int g = row >> 4, j = wg * 16 + (row & 15);
            const float* bi = (g == 0) ? bfi : (g == 1) ? bii : (g == 2) ? bci : boi;
            const float* bh = (g == 0) ? bfh : (g == 1) ? bih : (g == 2) ? bch : boh;
            bv = bi[j] + bh[j];
        }
        acc_init[rg] = bv;
    }

    const int bown = tid & 63;
    const int w8   = tid >> 6;
    const int j0   = wg * 16 + 2 * w8;
    float cst[2];
    {
        const f32x2 cv = *(const f32x2*)(c0 + bown * HH + j0);
        cst[0] = cv.x; cst[1] = cv.y;
    }

    #pragma unroll
    for (int i = 0; i < 4; ++i) {
        int cid = i * 512 + tid;
        int bq = cid >> 5, k8 = cid & 31;
        const f32x4* sp = (const f32x4*)(x + bq * II + k8 * 8);
        f32x4 v0 = sp[0], v1 = sp[1];
        u32x4 pk;
        pk.x = pk2h(v0[0], v0[1]); pk.y = pk2h(v0[2], v0[3]);
        pk.z = pk2h(v1[0], v1[1]); pk.w = pk2h(v1[2], v1[3]);
        *(u32x4*)&BSc[(k8 * 64 + (bq ^ (k8 & 7))) * 16] = pk;
    }

    for (int t = 0; t < SS; ++t) {
        const int cur = t & 1;
        float* GLp = (float*)(BSc + (size_t)(cur ^ 1) * 2048 * 16);

        {
            const u16* hsrc = hb + cur * (BB * HH);
            u64 hr[16];
            #pragma unroll
            for (int it = 0; it < 8; ++it) {
                int cd = it * 512 + tid;
                int k8h = cd >> 6, bpos = cd & 63;
                int bq = bpos ^ (k8h & 7);
                const u64* p = (const u64*)(hsrc + k8h * 512 + bq * 8);
                hr[2 * it]     = ld_u64_coh(p);
                hr[2 * it + 1] = ld_u64_coh(p + 1);
            }
            #pragma unroll
            for (int it = 0; it < 8; ++it) {
                int cd = it * 512 + tid;
                union { u64 q[2]; u32x4 v; } u;
                u.q[0] = hr[2 * it]; u.q[1] = hr[2 * it + 1];
                *(u32x4*)&BSc[(4096 + cd) * 16] = u.v;
            }
        }

        f32x4 xv[8];
        if (t + 1 < SS) {
            const float* xt = x + (size_t)(t + 1) * BB * II;
            #pragma unroll
            for (int i = 0; i < 4; ++i) {
                int cid = i * 512 + tid;
                int bq = cid >> 5, k8 = cid & 31;
                const f32x4* sp = (const f32x4*)(xt + bq * II + k8 * 8);
                xv[2 * i] = sp[0]; xv[2 * i + 1] = sp[1];
            }
        }

        __syncthreads();

        f32x16 acc = acc_init;
        #pragma unroll
        for (int kt = 0; kt < 24; ++kt) {
            int k8g = ks * 48 + kt * 2 + khi;
            int off;
            if (k8g < 32) { int q = k8g & 7;
                off = (cur * 2048 + k8g * 64 + ((nb ^ q))) * 16;
            } else {        int k8h = k8g - 32; int q = k8h & 7;
                off = (4096 + k8h * 64 + ((nb ^ q))) * 16;
            }
            h16x8 bf = *(const h16x8*)(BSc + off);
            acc = __builtin_amdgcn_mfma_f32_32x32x16_f16(afr[kt], bf, acc, 0, 0, 0);
        }

        #pragma unroll
        for (int rg = 0; rg < 16; ++rg) {
            int row = mt * 32 + (rg & 3) + 8 * (rg >> 2) + 4 * khi;
            GLp[ks * 4096 + row * 64 + nb] = acc[rg];
        }
        __syncthreads();

        float hv2[2];
        #pragma unroll
        for (int i = 0; i < 2; ++i) {
            int m = 2 * w8 + i;
            float af = GLp[(0 * 16 + m) * 64 + bown] + GLp[4096 + (0 * 16 + m) * 64 + bown];
            float ai = GLp[(1 * 16 + m) * 64 + bown] + GLp[4096 + (1 * 16 + m) * 64 + bown];
            float ac = GLp[(2 * 16 + m) * 64 + bown] + GLp[4096 + (2 * 16 + m) * 64 + bown];
            float ao = GLp[(3 * 16 + m) * 64 + bown] + GLp[4096 + (3 * 16 + m) * 64 + bown];
            float fg = sigf(af), ig = sigf(ai), cg = tanhf_(ac), og = sigf(ao);
            float cn = cst[i] * fg + ig * cg;
            cst[i] = cn;
            hv2[i] = og * tanhf_(cn);
        }
        {
            f32x2 ho; ho.x = hv2[0]; ho.y = hv2[1];
            *(f32x2*)(out + ((size_t)t * BB + bown) * HH + j0) = ho;
        }
        st_u32_coh((u32*)(hb + ((t + 1) & 1) * (BB * HH) + (j0 >> 3) * 512 + bown * 8 + (j0 & 7)),
                   pk2h(hv2[0], hv2[1]));

        if (t == SS - 1) {
            f32x2 ho; ho.x = hv2[0]; ho.y = hv2[1];
            f32x2 co; co.x = cst[0]; co.y = cst[1];
            *(f32x2*)(out + (size_t)SS * BB * HH + bown * HH + j0) = ho;
            *(f32x2*)(out + (size_t)SS * BB * HH + BB * HH + bown * HH + j0) = co;
            break;
        }

        __syncthreads();
        if (tid == 0) st_i32_coh(&flags[wg * 32], t + 1);

        #pragma unroll
        for (int i = 0; i < 4; ++i) {
            int cid = i * 512 + tid;
            int bq = cid >> 5, k8 = cid & 31;
            f32x4 v0 = xv[2 * i], v1 = xv[2 * i + 1];
            u32x4 pk;
            pk.x = pk2h(v0[0], v0[1]); pk.y = pk2h(v0[2], v0[3]);
            pk.z = pk2h(v1[0], v1[1]); pk.w = pk2h(v1[2], v1[3]);
            *(u32x4*)&BSc[((cur ^ 1) * 2048 + k8 * 64 + (bq ^ (k8 & 7))) * 16] = pk;
        }

        if (tid < 32) {
            while (ld_i32_coh(&flags[tid * 32]) < t + 1) {}
        }
        asm volatile("" ::: "memory");
        __syncthreads();
    }
}

extern "C" void kernel_launch(void* const* d_in, const int* in_sizes, int n_in,
                              void* d_out, int out_size, void* d_ws, size_t ws_size,
                              hipStream_t stream) {
    const float* x   = (const float*)d_in[0];
    const float* h0  = (const float*)d_in[1];
    const float* c0  = (const float*)d_in[2];
    const float* Wfi = (const float*)d_in[3];
    const float* bfi = (const float*)d_in[4];
    const float* Wfh = (const float*)d_in[5];
    const float* bfh = (const float*)d_in[6];
    const float* Wii = (const float*)d_in[7];
    const float* bii = (const float*)d_in[8];
    const float* Wih = (const float*)d_in[9];
    const float* bih = (const float*)d_in[10];
    const float* Wci = (const float*)d_in[11];
    const float* bci = (const float*)d_in[12];
    const float* Wch = (const float*)d_in[13];
    const float* bch = (const float*)d_in[14];
    const float* Woi = (const float*)d_in[15];
    const float* boi = (const float*)d_in[16];
    const float* Woh = (const float*)d_in[17];
    const float* boh = (const float*)d_in[18];

    if (ws_size >= WS_XP) {
        u32*   A2   = (u32*)((char*)d_ws + XA2_OFF);
        u32*   WXA  = (u32*)((char*)d_ws + XWXA_OFF);
        float* bsum = (float*)((char*)d_ws + XBS_OFF);
        u16*   hbb  = (u16*)((char*)d_ws + XHB_OFF);
        int*   flg  = (int*)((char*)d_ws + XFL_OFF);
        u64*   XPq  = (u64*)((char*)d_ws + XXP_OFF);

        xprep_pack<<<dim3((A2_DW + WXA_DW + GROW + 255) / 256), dim3(256), 0, stream>>>(
            Wfi, Wfh, Wii, Wih, Wci, Wch, Woi, Woh,
            bfi, bfh, bii, bih, bci, bch, boi, boh, A2, WXA, bsum);
        xprep_hb<<<dim3(128), dim3(256), 0, stream>>>(h0, hbb, flg);
        xproj<<<dim3(TBN / 128), dim3(512), 0, stream>>>(x, WXA, bsum, XPq);
        lstm_rec<<<dim3(NWG), dim3(512), 0, stream>>>(c0, A2, hbb, flg, XPq, (float*)d_out);
    } else {
        u32* A     = (u32*)d_ws;
        u16* hbb   = (u16*)((char*)d_ws + HB_OFF);
        int* flags = (int*)((char*)d_ws + FL_OFF);
        prep_A<<<dim3(A_DWORDS / 256), dim3(256), 0, stream>>>(
            Wfi, Wfh, Wii, Wih, Wci, Wch, Woi, Woh, A);
        prep_misc<<<dim3(128), dim3(256), 0, stream>>>(h0, hbb, flags);
        lstm_mfma<<<dim3(32), dim3(512), 0, stream>>>(
            x, c0, bfi, bfh, bii, bih, bci, bch, boi, boh,
            A, hbb, flags, (float*)d_out);
    }
}

// Round 9
// 1438.677 us; speedup vs baseline: 4.9286x; 4.9286x over previous
//
#include <hip/hip_runtime.h>

// LSTM S=512,B=64,I=256,H=512 (f32 buffers).
// R9: R8 failed on (1) runtime-indexed afr[] -> spilled to scratch (VGPR 68),
// (2) 8 waves redundantly streaming the same remote h (480KB/WG/step).
// Fix: 2-D split. 32 WGs = 8 hidden-groups x 4 batch-groups; WG owns 64
// hidden x 16 batches. h-exchange only within its 4-batch-group (8 WGs):
// ingest 16KB/step -> XOR-swizzled LDS (one load, 8 waves consume);
// publish 2KB via LDS gather -> 256 coalesced u64 coherent stores.
// mfma_f32_16x16x32_f16, two tiles/wave, STATIC afr indices; each lane
// holds all 4 gates of one unit per tile -> in-register pointwise.
// Sync: proven fence-free relaxed agent-scope protocol (R5).

#define SS 512
#define BB 64
#define II 256
#define HH 512
#define NWG 32
#define GROW 2048
#define TBN  (SS*BB)

typedef unsigned int u32;
typedef unsigned short u16;
typedef unsigned long long u64;
typedef _Float16 __attribute__((ext_vector_type(8))) h16x8;
typedef __attribute__((ext_vector_type(2))) float f32x2;
typedef __attribute__((ext_vector_type(4))) float f32x4;
typedef __attribute__((ext_vector_type(16))) float f32x16;
typedef u32 __attribute__((ext_vector_type(4))) u32x4;
typedef u32 __attribute__((ext_vector_type(2))) u32x2;

// ---------------- XP-path ws layout ----------------
#define A2_DW   (8 * 8 * 2 * 16 * 256)        // 524288 dwords = 2 MB (h A-frags)
#define WXA_DW  (64 * 16 * 256)               // 262144 dwords = 1 MB (x A-frags)
#define XA2_OFF  0
#define XWXA_OFF ((size_t)A2_DW * 4)                    // 2,097,152
#define XBS_OFF  (XWXA_OFF + (size_t)WXA_DW * 4)        // 3,145,728 (bsum 8 KB)
#define XHB_OFF  (XBS_OFF + 8192)                       // 3,153,920 (hb 128 KB)
#define XFL_OFF  (XHB_OFF + 2 * (size_t)BB * HH * 2)    // 3,284,992 (flags 2 KB)
#define XXP_OFF  ((size_t)4 * 1024 * 1024)              // 4,194,304
#define XP_BYTES ((size_t)GROW * TBN * 2)               // 134,217,728
#define WS_XP    (XXP_OFF + XP_BYTES)                   // 138,412,032

// ---------------- R5-fallback ws layout ----------------
#define A_DWORDS (32 * 2 * 2 * 24 * 64 * 4)           // 786432
#define HB_OFF   ((size_t)A_DWORDS * 4)               // 3,145,728
#define FL_OFF   (HB_OFF + 2 * (size_t)BB * HH * 2)   // +131,072
#define WS_NEED  (FL_OFF + 4096)

__device__ __forceinline__ u32 pk2h(float a, float b) {
    union { _Float16 h[2]; u32 u; } v;
    v.h[0] = (_Float16)a; v.h[1] = (_Float16)b; return v.u;
}
__device__ __forceinline__ u16 f2h(float a) {
    union { _Float16 h; u16 u; } v; v.h = (_Float16)a; return v.u;
}
__device__ __forceinline__ float h2f(u16 u) {
    union { u16 u; _Float16 h; } v; v.u = u; return (float)v.h;
}
__device__ __forceinline__ float sigf(float v)  { return 1.0f / (1.0f + __expf(-v)); }
__device__ __forceinline__ float tanhf_(float v){ return 1.0f - 2.0f / (1.0f + __expf(2.0f * v)); }

// relaxed agent-scope (coherent-at-L3, no cache-maintenance fences)
__device__ __forceinline__ void st_u32_coh(u32* p, u32 v) {
    __hip_atomic_store(p, v, __ATOMIC_RELAXED, __HIP_MEMORY_SCOPE_AGENT);
}
__device__ __forceinline__ void st_u64_coh(u64* p, u64 v) {
    __hip_atomic_store(p, v, __ATOMIC_RELAXED, __HIP_MEMORY_SCOPE_AGENT);
}
__device__ __forceinline__ void st_i32_coh(int* p, int v) {
    __hip_atomic_store(p, v, __ATOMIC_RELAXED, __HIP_MEMORY_SCOPE_AGENT);
}
__device__ __forceinline__ int ld_i32_coh(const int* p) {
    return __hip_atomic_load(p, __ATOMIC_RELAXED, __HIP_MEMORY_SCOPE_AGENT);
}
__device__ __forceinline__ u64 ld_u64_coh(const u64* p) {
    return __hip_atomic_load(p, __ATOMIC_RELAXED, __HIP_MEMORY_SCOPE_AGENT);
}

// ===================================================================
// XP path
// ===================================================================

// A2: h-weight A-frags for mfma_f32_16x16x32_f16.
//   dw idx = (((hg*8+mt)*2+tile)*16+ks)*256 + l*4 + d
//   row15 = l&15: ulocal = row15>>2, g = row15&3 (gate-minor);
//   j = hg*64 + mt*8 + tile*4 + ulocal; k = ks*32 + (l>>4)*8 + d*2.
// WXA/bsum: unchanged from R8 (32x32 xproj).
__global__ __launch_bounds__(256) void xprep_pack(
    const float* __restrict__ Wfi, const float* __restrict__ Wfh,
    const float* __restrict__ Wii, const float* __restrict__ Wih,
    const float* __restrict__ Wci, const float* __restrict__ Wch,
    const float* __restrict__ Woi, const float* __restrict__ Woh,
    const float* __restrict__ bfi, const float* __restrict__ bfh,
    const float* __restrict__ bii, const float* __restrict__ bih,
    const float* __restrict__ bci, const float* __restrict__ bch,
    const float* __restrict__ boi, const float* __restrict__ boh,
    u32* __restrict__ A2, u32* __restrict__ WXA, float* __restrict__ bsum)
{
    int tid = blockIdx.x * 256 + threadIdx.x;
    if (tid < A2_DW) {
        int d = tid & 3, l = (tid >> 2) & 63, ks = (tid >> 8) & 15;
        int tile = (tid >> 12) & 1, mt = (tid >> 13) & 7, hg = tid >> 16;
        int row15 = l & 15;
        int ulocal = row15 >> 2, g = row15 & 3;
        int j = hg * 64 + mt * 8 + tile * 4 + ulocal;
        int k = ks * 32 + (l >> 4) * 8 + d * 2;
        const float* Wh = (g == 0) ? Wfh : (g == 1) ? Wih : (g == 2) ? Wch : Woh;
        A2[tid] = pk2h(Wh[j * HH + k], Wh[j * HH + k + 1]);
    } else if (tid < A2_DW + WXA_DW) {
        int t2 = tid - A2_DW;
        int d = t2 & 3, l = (t2 >> 2) & 63, kt = (t2 >> 8) & 15, gt = t2 >> 12;
        int r = l & 31, g = r & 3;
        int j = gt * 8 + (r >> 2);
        int k = kt * 16 + (l >> 5) * 8 + d * 2;
        const float* Wi = (g == 0) ? Wfi : (g == 1) ? Wii : (g == 2) ? Wci : Woi;
        WXA[t2] = pk2h(Wi[j * II + k], Wi[j * II + k + 1]);
    } else if (tid < A2_DW + WXA_DW + GROW) {
        int grow = tid - A2_DW - WXA_DW;
        int r = grow & 31, gt = grow >> 5;
        int g = r & 3, j = gt * 8 + (r >> 2);
        const float* bi = (g == 0) ? bfi : (g == 1) ? bii : (g == 2) ? bci : boi;
        const float* bh = (g == 0) ? bfh : (g == 1) ? bih : (g == 2) ? bch : boh;
        bsum[grow] = bi[j] + bh[j];
    }
}

// hb layout: [buf 2][b 64][k 512] f16  (== [buf][bg][bl][k], bg = b>>4)
__global__ __launch_bounds__(256) void xprep_hb(
    const float* __restrict__ h0, u16* __restrict__ hb, int* __restrict__ flags)
{
    int tid = blockIdx.x * 256 + threadIdx.x;   // < 32768
    if (tid < BB * HH) hb[tid] = f2h(h0[tid]);
    if (tid < NWG) flags[tid * 16] = 0;         // 64B-strided flags
}

// xproj: XPq[(j*512 + t)*64 + b] = u64 of 4 f16 gates {f,i,c,o} of unit j.
// (unchanged from R8 — 32x32x16 MFMA, verified on-device)
__global__ __launch_bounds__(512, 1) void xproj(
    const float* __restrict__ x, const u32* __restrict__ WXA,
    const float* __restrict__ bsum, u64* __restrict__ XPq)
{
    const int wgid = blockIdx.x;
    const int tid = threadIdx.x, lane = tid & 63, w = tid >> 6;
    const int TB0 = wgid * 128;
    __shared__ __align__(16) u32 XB[32 * 128 * 4];

    #pragma unroll
    for (int it = 0; it < 16; ++it) {
        int c = it * 512 + tid;
        int m = c >> 6, ck = c & 63;
        f32x4 v = *(const f32x4*)(x + (size_t)(TB0 + m) * II + ck * 4);
        u32x2 p; p.x = pk2h(v.x, v.y); p.y = pk2h(v.z, v.w);
        *(u32x2*)(XB + ((ck >> 1) * 128 + m) * 4 + (ck & 1) * 2) = p;
    }
    __syncthreads();

    const int gtw = w & 3, nh = w >> 2;
    const int khi = lane >> 5;
    for (int nt = 0; nt < 2; ++nt) {
        const int col = nh * 64 + nt * 32 + (lane & 31);
        const int tb = TB0 + col;
        const int t_ = tb >> 6, b_ = tb & 63;
        h16x8 bfr[16];
        #pragma unroll
        for (int kt = 0; kt < 16; ++kt)
            bfr[kt] = *(const h16x8*)(XB + ((kt * 2 + khi) * 128 + col) * 4);
        for (int gti = 0; gti < 16; ++gti) {
            const int gt = gtw * 16 + gti;
            f32x16 acc;
            #pragma unroll
            for (int rg = 0; rg < 16; ++rg)
                acc[rg] = bsum[gt * 32 + (rg & 3) + 8 * (rg >> 2) + 4 * khi];
            const u32* ap = WXA + (size_t)(gt * 16) * 256 + lane * 4;
            #pragma unroll
            for (int kt = 0; kt < 16; ++kt) {
                h16x8 af = *(const h16x8*)(ap + kt * 256);
                acc = __builtin_amdgcn_mfma_f32_32x32x16_f16(af, bfr[kt], acc, 0, 0, 0);
            }
            #pragma unroll
            for (int q = 0; q < 4; ++q) {
                int j = gt * 8 + 2 * q + khi;
                union { u16 s[4]; u64 u; } pk;
                pk.s[0] = f2h(acc[4 * q + 0]);
                pk.s[1] = f2h(acc[4 * q + 1]);
                pk.s[2] = f2h(acc[4 * q + 2]);
                pk.s[3] = f2h(acc[4 * q + 3]);
                XPq[((size_t)j * 512 + t_) * 64 + b_] = pk.u;
            }
        }
    }
}

// recurrent: 2-D split. WG (hg = wg>>2, bg = wg&3): 64 hidden x 16 batches.
__global__ __launch_bounds__(512, 2) void lstm_rec(
    const float* __restrict__ c0,
    const u32* __restrict__ A2, u16* __restrict__ hb, int* __restrict__ flags,
    const u64* __restrict__ XPq, float* __restrict__ out)
{
    const int wg = blockIdx.x;
    const int hg = wg >> 2, bg = wg & 3;
    const int tid = threadIdx.x, lane = tid & 63, mt = tid >> 6;
    const int bl = lane & 15;          // batch-local (MFMA col)
    const int kq = lane >> 4;          // k-quarter / ulocal (0..3)
    const int b  = bg * 16 + bl;       // global batch

    __shared__ __align__(16) u16 HL[16 * 512];   // 16 KB, XOR-swizzled [bl][k]
    __shared__ __align__(16) u16 hst[16 * 64];   // 2 KB publish gather [bl][jl]
    u64* hb64  = (u64*)hb;
    u64* hst64 = (u64*)hst;
    char* HLc  = (char*)HL;

    // A fragments, STATIC indices (rule #20): 2 tiles x 16 ks x 4 VGPR = 128
    h16x8 afr0[16], afr1[16];
    {
        const u32* a0 = A2 + ((size_t)((hg * 8 + mt) * 2 + 0) * 16) * 256 + lane * 4;
        const u32* a1 = A2 + ((size_t)((hg * 8 + mt) * 2 + 1) * 16) * 256 + lane * 4;
        #pragma unroll
        for (int ks = 0; ks < 16; ++ks) {
            afr0[ks] = *(const h16x8*)(a0 + ks * 256);
            afr1[ks] = *(const h16x8*)(a1 + ks * 256);
        }
    }

    // units this lane owns (one per tile; all 4 gates in acc regs)
    const int j0 = hg * 64 + mt * 8 + kq;      // tile 0
    const int j1 = j0 + 4;                     // tile 1

    float cst0 = c0[b * HH + j0];
    float cst1 = c0[b * HH + j1];

    for (int t = 0; t < SS; ++t) {
        // XP prefetch (plain cached loads, before the spin)
        u64 xq0 = XPq[((size_t)j0 * SS + t) * BB + b];
        u64 xq1 = XPq[((size_t)j1 * SS + t) * BB + b];

        // spin: lane-parallel poll of the 8 producers of this bg-group
        if (tid < 8) { while (ld_i32_coh(&flags[(bg * 8 + tid) * 16]) < t) {} }
        asm volatile("" ::: "memory");
        __syncthreads();

        // ingest 16 KB slice -> swizzled LDS (4 coalesced u64 loads/thread)
        {
            const u64* src = hb64 + (size_t)(t & 1) * 8192 + bg * 2048;
            u64 v0 = ld_u64_coh(src + 0 * 512 + tid);
            u64 v1 = ld_u64_coh(src + 1 * 512 + tid);
            u64 v2 = ld_u64_coh(src + 2 * 512 + tid);
            u64 v3 = ld_u64_coh(src + 3 * 512 + tid);
            #pragma unroll
            for (int i = 0; i < 4; ++i) {
                u64 v = (i == 0) ? v0 : (i == 1) ? v1 : (i == 2) ? v2 : v3;
                int idx = i * 512 + tid;          // u64 index in slice
                int row = idx >> 7, k8 = idx & 127;
                *(u64*)(HLc + row * 1024 + ((k8 * 8) ^ ((row & 7) << 4))) = v;
            }
        }
        __syncthreads();

        // K-loop: 16 ds_read_b128 (shared) + 32 MFMAs 16x16x32
        f32x4 acc0 = {0.f, 0.f, 0.f, 0.f}, acc1 = {0.f, 0.f, 0.f, 0.f};
        #pragma unroll
        for (int ks = 0; ks < 16; ++ks) {
            const int koff = ks * 64 + kq * 16;   // byte offset of this 8-f16 span
            h16x8 bf = *(const h16x8*)(HLc + bl * 1024 + (koff ^ ((bl & 7) << 4)));
            acc0 = __builtin_amdgcn_mfma_f32_16x16x32_f16(afr0[ks], bf, acc0, 0, 0, 0);
            acc1 = __builtin_amdgcn_mfma_f32_16x16x32_f16(afr1[ks], bf, acc1, 0, 0, 0);
        }

        // in-register pointwise (acc reg index == gate, per m89 C/D layout)
        float hv0, hv1;
        {
            union { u64 u; u16 s[4]; } xu; xu.u = xq0;
            float af = acc0[0] + h2f(xu.s[0]);
            float ai = acc0[1] + h2f(xu.s[1]);
            float ac = acc0[2] + h2f(xu.s[2]);
            float ao = acc0[3] + h2f(xu.s[3]);
            float cn = cst0 * sigf(af) + sigf(ai) * tanhf_(ac);
            cst0 = cn; hv0 = sigf(ao) * tanhf_(cn);
        }
        {
            union { u64 u; u16 s[4]; } xu; xu.u = xq1;
            float af = acc1[0] + h2f(xu.s[0]);
            float ai = acc1[1] + h2f(xu.s[1]);
            float ac = acc1[2] + h2f(xu.s[2]);
            float ao = acc1[3] + h2f(xu.s[3]);
            float cn = cst1 * sigf(af) + sigf(ai) * tanhf_(ac);
            cst1 = cn; hv1 = sigf(ao) * tanhf_(cn);
        }
        hst[bl * 64 + mt * 8 + kq]     = f2h(hv0);
        hst[bl * 64 + mt * 8 + 4 + kq] = f2h(hv1);

        if (t < SS - 1) {
            __syncthreads();   // hst complete
            if (tid < 256) {
                int blr = tid >> 4, ju = tid & 15;   // 16 u64 per bl-row
                st_u64_coh(hb64 + (size_t)((t + 1) & 1) * 8192 + bg * 2048
                               + blr * 128 + hg * 16 + ju,
                           hst64[tid]);
            }
            __syncthreads();   // vmcnt(0) drain -> stores visible at L3
            if (tid == 0) st_i32_coh(&flags[(bg * 8 + hg) * 16], t + 1);
        }

        // out stores after flag publish (drain hides in next step)
        out[((size_t)t * BB + b) * HH + j0] = hv0;
        out[((size_t)t * BB + b) * HH + j1] = hv1;
        if (t == SS - 1) {
            out[(size_t)SS * BB * HH + b * HH + j0] = hv0;
            out[(size_t)SS * BB * HH + b * HH + j1] = hv1;
            out[(size_t)SS * BB * HH + BB * HH + b * HH + j0] = cst0;
            out[(size_t)SS * BB * HH + BB * HH + b * HH + j1] = cst1;
        }
    }
}

// ===================================================================
// R5 fallback path (proven 2.63 ms) — verbatim
// ===================================================================
__global__ __launch_bounds__(256) void prep_A(
    const float* __restrict__ Wfi, const float* __restrict__ Wfh,
    const float* __restrict__ Wii, const float* __restrict__ Wih,
    const float* __restrict__ Wci, const float* __restrict__ Wch,
    const float* __restrict__ Woi, const float* __restrict__ Woh,
    u32* __restrict__ A)
{
    int tid = blockIdx.x * 256 + threadIdx.x;
    int wg = tid / 24576;  int r = tid - wg * 24576;
    int mt = r / 12288;    r -= mt * 12288;
    int ks = r / 6144;     r -= ks * 6144;
    int kt = r / 256;      r -= kt * 256;
    int l  = r >> 2;       int d = r & 3;

    int row = mt * 32 + (l & 31);
    int g   = row >> 4;
    int j   = wg * 16 + (row & 15);
    int k   = ks * 384 + kt * 16 + (l >> 5) * 8 + d * 2;

    const float* Wi = (g == 0) ? Wfi : (g == 1) ? Wii : (g == 2) ? Wci : Woi;
    const float* Wh = (g == 0) ? Wfh : (g == 1) ? Wih : (g == 2) ? Wch : Woh;
    float w0, w1;
    if (k < II) { w0 = Wi[j * II + k];        w1 = Wi[j * II + k + 1]; }
    else        { int kk = k - II; w0 = Wh[j * HH + kk]; w1 = Wh[j * HH + kk + 1]; }
    A[tid] = pk2h(w0, w1);
}

__global__ __launch_bounds__(256) void prep_misc(
    const float* __restrict__ h0, u16* __restrict__ hb, int* __restrict__ flags)
{
    int tid = blockIdx.x * 256 + threadIdx.x;
    if (tid < BB * HH) {
        int b = tid >> 9, j = tid & 511;
        hb[(j >> 3) * 512 + b * 8 + (j & 7)] = f2h(h0[tid]);
    }
    if (tid < 32) flags[tid * 32] = 0;
}

__global__ __launch_bounds__(512, 1) void lstm_mfma(
    const float* __restrict__ x,  const float* __restrict__ c0,
    const float* __restrict__ bfi, const float* __restrict__ bfh,
    const float* __restrict__ bii, const float* __restrict__ bih,
    const float* __restrict__ bci, const float* __restrict__ bch,
    const float* __restrict__ boi, const float* __restrict__ boh,
    const u32* __restrict__ A, u16* __restrict__ hb, int* __restrict__ flags,
    float* __restrict__ out)
{
    const int wg   = blockIdx.x;
    const int tid  = threadIdx.x;
    const int lane = tid & 63;
    const int w    = tid >> 6;
    const int mt   = w & 1;
    const int nt2  = (w >> 1) & 1;
    const int ks   = w >> 2;
    const int khi  = lane >> 5;
    const int nb   = nt2 * 32 + (lane & 31);

    __shared__ __align__(16) u16 BS[8192 * 8];
    char* BSc = (char*)BS;

    h16x8 afr[24];
    {
        const u32* ab = A + ((wg * 2 + mt) * 2 + ks) * (24 * 256) + lane * 4;
        #pragma unroll
        for (int kt = 0; kt < 24; ++kt)
            afr[kt] = *(const h16x8*)(ab + kt * 256);
    }

    f32x16 acc_init;
    #pragma unroll
    for (int rg = 0; rg < 16; ++rg) {
        int row = mt * 32 + (rg & 3) + 8 * (rg >> 2) + 4 * khi;
        float bv = 0.0f;
        if (ks == 0) {
            int g = row >> 4, j = wg * 16 + (row & 15);
            const float* bi = (g == 0) ? bfi : (g == 1) ? bii : (g == 2) ? bci : boi;
            const float* bh = (g == 0) ? bfh : (g == 1) ? bih : (g == 2) ? bch : boh;
            bv = bi[j] + bh[j];
        }
        acc_init[rg] = bv;
    }

    const int bown = tid & 63;
    const int w8   = tid >> 6;
    const int j0   = wg * 16 + 2 * w8;
    float cst[2];
    {
        const f32x2 cv = *(const f32x2*)(c0 + bown * HH + j0);
        cst[0] = cv.x; cst[1] = cv.y;
    }

    #pragma unroll
    for (int i = 0; i < 4; ++i) {
        int cid = i * 512 + tid;
        int bq = cid >> 5, k8 = cid & 31;
        const f32x4* sp = (const f32x4*)(x + bq * II + k8 * 8);
        f32x4 v0 = sp[0], v1 = sp[1];
        u32x4 pk;
        pk.x = pk2h(v0[0], v0[1]); pk.y = pk2h(v0[2], v0[3]);
        pk.z = pk2h(v1[0], v1[1]); pk.w = pk2h(v1[2], v1[3]);
        *(u32x4*)&BSc[(k8 * 64 + (bq ^ (k8 & 7))) * 16] = pk;
    }

    for (int t = 0; t < SS; ++t) {
        const int cur = t & 1;
        float* GLp = (float*)(BSc + (size_t)(cur ^ 1) * 2048 * 16);

        {
            const u16* hsrc = hb + cur * (BB * HH);
            u64 hr[16];
            #pragma unroll
            for (int it = 0; it < 8; ++it) {
                int cd = it * 512 + tid;
                int k8h = cd >> 6, bpos = cd & 63;
                int bq = bpos ^ (k8h & 7);
                const u64* p = (const u64*)(hsrc + k8h * 512 + bq * 8);
                hr[2 * it]     = ld_u64_coh(p);
                hr[2 * it + 1] = ld_u64_coh(p + 1);
            }
            #pragma unroll
            for (int it = 0; it < 8; ++it) {
                int cd = it * 512 + tid;
                union { u64 q[2]; u32x4 v; } u;
                u.q[0] = hr[2 * it]; u.q[1] = hr[2 * it + 1];
                *(u32x4*)&BSc[(4096 + cd) * 16] = u.v;
            }
        }

        f32x4 xv[8];
        if (t + 1 < SS) {
            const float* xt = x + (size_t)(t + 1) * BB * II;
            #pragma unroll
            for (int i = 0; i < 4; ++i) {
                int cid = i * 512 + tid;
                int bq = cid >> 5, k8 = cid & 31;
                const f32x4* sp = (const f32x4*)(xt + bq * II + k8 * 8);
                xv[2 * i] = sp[0]; xv[2 * i + 1] = sp[1];
            }
        }

        __syncthreads();

        f32x16 acc = acc_init;
        #pragma unroll
        for (int kt = 0; kt < 24; ++kt) {
            int k8g = ks * 48 + kt * 2 + khi;
            int off;
            if (k8g < 32) { int q = k8g & 7;
                off = (cur * 2048 + k8g * 64 + ((nb ^ q))) * 16;
            } else {        int k8h = k8g - 32; int q = k8h & 7;
                off = (4096 + k8h * 64 + ((nb ^ q))) * 16;
            }
            h16x8 bf = *(const h16x8*)(BSc + off);
            acc = __builtin_amdgcn_mfma_f32_32x32x16_f16(afr[kt], bf, acc, 0, 0, 0);
        }

        #pragma unroll
        for (int rg = 0; rg < 16; ++rg) {
            int row = mt * 32 + (rg & 3) + 8 * (rg >> 2) + 4 * khi;
            GLp[ks * 4096 + row * 64 + nb] = acc[rg];
        }
        __syncthreads();

        float hv2[2];
        #pragma unroll
        for (int i = 0; i < 2; ++i) {
            int m = 2 * w8 + i;
            float af = GLp[(0 * 16 + m) * 64 + bown] + GLp[4096 + (0 * 16 + m) * 64 + bown];
            float ai = GLp[(1 * 16 + m) * 64 + bown] + GLp[4096 + (1 * 16 + m) * 64 + bown];
            float ac = GLp[(2 * 16 + m) * 64 + bown] + GLp[4096 + (2 * 16 + m) * 64 + bown];
            float ao = GLp[(3 * 16 + m) * 64 + bown] + GLp[4096 + (3 * 16 + m) * 64 + bown];
            float fg = sigf(af), ig = sigf(ai), cg = tanhf_(ac), og = sigf(ao);
            float cn = cst[i] * fg + ig * cg;
            cst[i] = cn;
            hv2[i] = og * tanhf_(cn);
        }
        {
            f32x2 ho; ho.x = hv2[0]; ho.y = hv2[1];
            *(f32x2*)(out + ((size_t)t * BB + bown) * HH + j0) = ho;
        }
        st_u32_coh((u32*)(hb + ((t + 1) & 1) * (BB * HH) + (j0 >> 3) * 512 + bown * 8 + (j0 & 7)),
                   pk2h(hv2[0], hv2[1]));

        if (t == SS - 1) {
            f32x2 ho; ho.x = hv2[0]; ho.y = hv2[1];
            f32x2 co; co.x = cst[0]; co.y = cst[1];
            *(f32x2*)(out + (size_t)SS * BB * HH + bown * HH + j0) = ho;
            *(f32x2*)(out + (size_t)SS * BB * HH + BB * HH + bown * HH + j0) = co;
            break;
        }

        __syncthreads();
        if (tid == 0) st_i32_coh(&flags[wg * 32], t + 1);

        #pragma unroll
        for (int i = 0; i < 4; ++i) {
            int cid = i * 512 + tid;
            int bq = cid >> 5, k8 = cid & 31;
            f32x4 v0 = xv[2 * i], v1 = xv[2 * i + 1];
            u32x4 pk;
            pk.x = pk2h(v0[0], v0[1]); pk.y = pk2h(v0[2], v0[3]);
            pk.z = pk2h(v1[0], v1[1]); pk.w = pk2h(v1[2], v1[3]);
            *(u32x4*)&BSc[((cur ^ 1) * 2048 + k8 * 64 + (bq ^ (k8 & 7))) * 16] = pk;
        }

        if (tid < 32) {
            while (ld_i32_coh(&flags[tid * 32]) < t + 1) {}
        }
        asm volatile("" ::: "memory");
        __syncthreads();
    }
}

extern "C" void kernel_launch(void* const* d_in, const int* in_sizes, int n_in,
                              void* d_out, int out_size, void* d_ws, size_t ws_size,
                              hipStream_t stream) {
    const float* x   = (const float*)d_in[0];
    const float* h0  = (const float*)d_in[1];
    const float* c0  = (const float*)d_in[2];
    const float* Wfi = (const float*)d_in[3];
    const float* bfi = (const float*)d_in[4];
    const float* Wfh = (const float*)d_in[5];
    const float* bfh = (const float*)d_in[6];
    const float* Wii = (const float*)d_in[7];
    const float* bii = (const float*)d_in[8];
    const float* Wih = (const float*)d_in[9];
    const float* bih = (const float*)d_in[10];
    const float* Wci = (const float*)d_in[11];
    const float* bci = (const float*)d_in[12];
    const float* Wch = (const float*)d_in[13];
    const float* bch = (const float*)d_in[14];
    const float* Woi = (const float*)d_in[15];
    const float* boi = (const float*)d_in[16];
    const float* Woh = (const float*)d_in[17];
    const float* boh = (const float*)d_in[18];

    if (ws_size >= WS_XP) {
        u32*   A2   = (u32*)((char*)d_ws + XA2_OFF);
        u32*   WXA  = (u32*)((char*)d_ws + XWXA_OFF);
        float* bsum = (float*)((char*)d_ws + XBS_OFF);
        u16*   hbb  = (u16*)((char*)d_ws + XHB_OFF);
        int*   flg  = (int*)((char*)d_ws + XFL_OFF);
        u64*   XPq  = (u64*)((char*)d_ws + XXP_OFF);

        xprep_pack<<<dim3((A2_DW + WXA_DW + GROW + 255) / 256), dim3(256), 0, stream>>>(
            Wfi, Wfh, Wii, Wih, Wci, Wch, Woi, Woh,
            bfi, bfh, bii, bih, bci, bch, boi, boh, A2, WXA, bsum);
        xprep_hb<<<dim3(128), dim3(256), 0, stream>>>(h0, hbb, flg);
        xproj<<<dim3(TBN / 128), dim3(512), 0, stream>>>(x, WXA, bsum, XPq);
        lstm_rec<<<dim3(NWG), dim3(512), 0, stream>>>(c0, A2, hbb, flg, XPq, (float*)d_out);
    } else {
        u32* A     = (u32*)d_ws;
        u16* hbb   = (u16*)((char*)d_ws + HB_OFF);
        int* flags = (int*)((char*)d_ws + FL_OFF);
        prep_A<<<dim3(A_DWORDS / 256), dim3(256), 0, stream>>>(
            Wfi, Wfh, Wii, Wih, Wci, Wch, Woi, Woh, A);
        prep_misc<<<dim3(128), dim3(256), 0, stream>>>(h0, hbb, flags);
        lstm_mfma<<<dim3(32), dim3(512), 0, stream>>>(
            x, c0, bfi, bfh, bii, bih, bci, bch, boi, boh,
            A, hbb, flags, (float*)d_out);
    }
}

// Round 10
// 1398.983 us; speedup vs baseline: 5.0684x; 1.0284x over previous
//
#include <hip/hip_runtime.h>

// LSTM S=512,B=64,I=256,H=512 (f32 buffers).
// R10: R9 (1.44ms) left 16.25M LDS bank conflicts on the ds_read->MFMA
// critical path ([bl][k] layout: bank depended only on koff^swz -> 8-way).
// Fix: k-major HL16[k8][bl^(k8&7)] -> wave-linear 1KB reads (0 conflicts),
// conflict-free transposing ingest writes; hst u16 swizzle (jl ^ (bl&7)<<3)
// with exact-inverse publish gather. MFMA fragment semantics unchanged
// from R9 (verified passing). Sync: fence-free relaxed agent-scope (R5).

#define SS 512
#define BB 64
#define II 256
#define HH 512
#define NWG 32
#define GROW 2048
#define TBN  (SS*BB)

typedef unsigned int u32;
typedef unsigned short u16;
typedef unsigned long long u64;
typedef _Float16 __attribute__((ext_vector_type(8))) h16x8;
typedef __attribute__((ext_vector_type(2))) float f32x2;
typedef __attribute__((ext_vector_type(4))) float f32x4;
typedef __attribute__((ext_vector_type(16))) float f32x16;
typedef u32 __attribute__((ext_vector_type(4))) u32x4;
typedef u32 __attribute__((ext_vector_type(2))) u32x2;

// ---------------- XP-path ws layout ----------------
#define A2_DW   (8 * 8 * 2 * 16 * 256)        // 524288 dwords = 2 MB (h A-frags)
#define WXA_DW  (64 * 16 * 256)               // 262144 dwords = 1 MB (x A-frags)
#define XA2_OFF  0
#define XWXA_OFF ((size_t)A2_DW * 4)                    // 2,097,152
#define XBS_OFF  (XWXA_OFF + (size_t)WXA_DW * 4)        // 3,145,728 (bsum 8 KB)
#define XHB_OFF  (XBS_OFF + 8192)                       // 3,153,920 (hb 128 KB)
#define XFL_OFF  (XHB_OFF + 2 * (size_t)BB * HH * 2)    // 3,284,992 (flags 2 KB)
#define XXP_OFF  ((size_t)4 * 1024 * 1024)              // 4,194,304
#define XP_BYTES ((size_t)GROW * TBN * 2)               // 134,217,728
#define WS_XP    (XXP_OFF + XP_BYTES)                   // 138,412,032

// ---------------- R5-fallback ws layout ----------------
#define A_DWORDS (32 * 2 * 2 * 24 * 64 * 4)           // 786432
#define HB_OFF   ((size_t)A_DWORDS * 4)               // 3,145,728
#define FL_OFF   (HB_OFF + 2 * (size_t)BB * HH * 2)   // +131,072
#define WS_NEED  (FL_OFF + 4096)

__device__ __forceinline__ u32 pk2h(float a, float b) {
    union { _Float16 h[2]; u32 u; } v;
    v.h[0] = (_Float16)a; v.h[1] = (_Float16)b; return v.u;
}
__device__ __forceinline__ u16 f2h(float a) {
    union { _Float16 h; u16 u; } v; v.h = (_Float16)a; return v.u;
}
__device__ __forceinline__ float h2f(u16 u) {
    union { u16 u; _Float16 h; } v; v.u = u; return (float)v.h;
}
__device__ __forceinline__ float sigf(float v)  { return 1.0f / (1.0f + __expf(-v)); }
__device__ __forceinline__ float tanhf_(float v){ return 1.0f - 2.0f / (1.0f + __expf(2.0f * v)); }

// relaxed agent-scope (coherent-at-L3, no cache-maintenance fences)
__device__ __forceinline__ void st_u32_coh(u32* p, u32 v) {
    __hip_atomic_store(p, v, __ATOMIC_RELAXED, __HIP_MEMORY_SCOPE_AGENT);
}
__device__ __forceinline__ void st_u64_coh(u64* p, u64 v) {
    __hip_atomic_store(p, v, __ATOMIC_RELAXED, __HIP_MEMORY_SCOPE_AGENT);
}
__device__ __forceinline__ void st_i32_coh(int* p, int v) {
    __hip_atomic_store(p, v, __ATOMIC_RELAXED, __HIP_MEMORY_SCOPE_AGENT);
}
__device__ __forceinline__ int ld_i32_coh(const int* p) {
    return __hip_atomic_load(p, __ATOMIC_RELAXED, __HIP_MEMORY_SCOPE_AGENT);
}
__device__ __forceinline__ u64 ld_u64_coh(const u64* p) {
    return __hip_atomic_load(p, __ATOMIC_RELAXED, __HIP_MEMORY_SCOPE_AGENT);
}

// ===================================================================
// XP path
// ===================================================================

// A2: h-weight A-frags for mfma_f32_16x16x32_f16 (unchanged from R9).
__global__ __launch_bounds__(256) void xprep_pack(
    const float* __restrict__ Wfi, const float* __restrict__ Wfh,
    const float* __restrict__ Wii, const float* __restrict__ Wih,
    const float* __restrict__ Wci, const float* __restrict__ Wch,
    const float* __restrict__ Woi, const float* __restrict__ Woh,
    const float* __restrict__ bfi, const float* __restrict__ bfh,
    const float* __restrict__ bii, const float* __restrict__ bih,
    const float* __restrict__ bci, const float* __restrict__ bch,
    const float* __restrict__ boi, const float* __restrict__ boh,
    u32* __restrict__ A2, u32* __restrict__ WXA, float* __restrict__ bsum)
{
    int tid = blockIdx.x * 256 + threadIdx.x;
    if (tid < A2_DW) {
        int d = tid & 3, l = (tid >> 2) & 63, ks = (tid >> 8) & 15;
        int tile = (tid >> 12) & 1, mt = (tid >> 13) & 7, hg = tid >> 16;
        int row15 = l & 15;
        int ulocal = row15 >> 2, g = row15 & 3;
        int j = hg * 64 + mt * 8 + tile * 4 + ulocal;
        int k = ks * 32 + (l >> 4) * 8 + d * 2;
        const float* Wh = (g == 0) ? Wfh : (g == 1) ? Wih : (g == 2) ? Wch : Woh;
        A2[tid] = pk2h(Wh[j * HH + k], Wh[j * HH + k + 1]);
    } else if (tid < A2_DW + WXA_DW) {
        int t2 = tid - A2_DW;
        int d = t2 & 3, l = (t2 >> 2) & 63, kt = (t2 >> 8) & 15, gt = t2 >> 12;
        int r = l & 31, g = r & 3;
        int j = gt * 8 + (r >> 2);
        int k = kt * 16 + (l >> 5) * 8 + d * 2;
        const float* Wi = (g == 0) ? Wfi : (g == 1) ? Wii : (g == 2) ? Wci : Woi;
        WXA[t2] = pk2h(Wi[j * II + k], Wi[j * II + k + 1]);
    } else if (tid < A2_DW + WXA_DW + GROW) {
        int grow = tid - A2_DW - WXA_DW;
        int r = grow & 31, gt = grow >> 5;
        int g = r & 3, j = gt * 8 + (r >> 2);
        const float* bi = (g == 0) ? bfi : (g == 1) ? bii : (g == 2) ? bci : boi;
        const float* bh = (g == 0) ? bfh : (g == 1) ? bih : (g == 2) ? bch : boh;
        bsum[grow] = bi[j] + bh[j];
    }
}

// hb layout: [buf 2][b 64][k 512] f16
__global__ __launch_bounds__(256) void xprep_hb(
    const float* __restrict__ h0, u16* __restrict__ hb, int* __restrict__ flags)
{
    int tid = blockIdx.x * 256 + threadIdx.x;   // < 32768
    if (tid < BB * HH) hb[tid] = f2h(h0[tid]);
    if (tid < NWG) flags[tid * 16] = 0;         // 64B-strided flags
}

// xproj: XPq[(j*512 + t)*64 + b] = u64 of 4 f16 gates {f,i,c,o} of unit j.
// (unchanged from R8/R9 — verified on-device)
__global__ __launch_bounds__(512, 1) void xproj(
    const float* __restrict__ x, const u32* __restrict__ WXA,
    const float* __restrict__ bsum, u64* __restrict__ XPq)
{
    const int wgid = blockIdx.x;
    const int tid = threadIdx.x, lane = tid & 63, w = tid >> 6;
    const int TB0 = wgid * 128;
    __shared__ __align__(16) u32 XB[32 * 128 * 4];

    #pragma unroll
    for (int it = 0; it < 16; ++it) {
        int c = it * 512 + tid;
        int m = c >> 6, ck = c & 63;
        f32x4 v = *(const f32x4*)(x + (size_t)(TB0 + m) * II + ck * 4);
        u32x2 p; p.x = pk2h(v.x, v.y); p.y = pk2h(v.z, v.w);
        *(u32x2*)(XB + ((ck >> 1) * 128 + m) * 4 + (ck & 1) * 2) = p;
    }
    __syncthreads();

    const int gtw = w & 3, nh = w >> 2;
    const int khi = lane >> 5;
    for (int nt = 0; nt < 2; ++nt) {
        const int col = nh * 64 + nt * 32 + (lane & 31);
        const int tb = TB0 + col;
        const int t_ = tb >> 6, b_ = tb & 63;
        h16x8 bfr[16];
        #pragma unroll
        for (int kt = 0; kt < 16; ++kt)
            bfr[kt] = *(const h16x8*)(XB + ((kt * 2 + khi) * 128 + col) * 4);
        for (int gti = 0; gti < 16; ++gti) {
            const int gt = gtw * 16 + gti;
            f32x16 acc;
            #pragma unroll
            for (int rg = 0; rg < 16; ++rg)
                acc[rg] = bsum[gt * 32 + (rg & 3) + 8 * (rg >> 2) + 4 * khi];
            const u32* ap = WXA + (size_t)(gt * 16) * 256 + lane * 4;
            #pragma unroll
            for (int kt = 0; kt < 16; ++kt) {
                h16x8 af = *(const h16x8*)(ap + kt * 256);
                acc = __builtin_amdgcn_mfma_f32_32x32x16_f16(af, bfr[kt], acc, 0, 0, 0);
            }
            #pragma unroll
            for (int q = 0; q < 4; ++q) {
                int j = gt * 8 + 2 * q + khi;
                union { u16 s[4]; u64 u; } pk;
                pk.s[0] = f2h(acc[4 * q + 0]);
                pk.s[1] = f2h(acc[4 * q + 1]);
                pk.s[2] = f2h(acc[4 * q + 2]);
                pk.s[3] = f2h(acc[4 * q + 3]);
                XPq[((size_t)j * 512 + t_) * 64 + b_] = pk.u;
            }
        }
    }
}

// recurrent: 2-D split (8 hg x 4 bg), conflict-free k-major LDS.
__global__ __launch_bounds__(512, 2) void lstm_rec(
    const float* __restrict__ c0,
    const u32* __restrict__ A2, u16* __restrict__ hb, int* __restrict__ flags,
    const u64* __restrict__ XPq, float* __restrict__ out)
{
    const int wg = blockIdx.x;
    const int hg = wg >> 2, bg = wg & 3;
    const int tid = threadIdx.x, lane = tid & 63, mt = tid >> 6;
    const int bl = lane & 15;          // batch-local (MFMA col)
    const int kq = lane >> 4;          // k-quarter / ulocal (0..3)
    const int b  = bg * 16 + bl;       // global batch

    // HL16[k8 64][b^ 16] 16B entries, k-major: reads wave-linear (0-conflict),
    // transposing writes 4 accesses/bank = min phases (0-conflict).
    __shared__ __align__(16) u16 HL[64 * 16 * 8];   // 16 KB
    __shared__ __align__(16) u16 hst[16 * 64];      // 2 KB publish gather
    u64* hb64  = (u64*)hb;
    u64* hst64 = (u64*)hst;
    char* HLc  = (char*)HL;

    // A fragments, STATIC indices: 2 tiles x 16 ks x 4 VGPR = 128
    h16x8 afr0[16], afr1[16];
    {
        const u32* a0 = A2 + ((size_t)((hg * 8 + mt) * 2 + 0) * 16) * 256 + lane * 4;
        const u32* a1 = A2 + ((size_t)((hg * 8 + mt) * 2 + 1) * 16) * 256 + lane * 4;
        #pragma unroll
        for (int ks = 0; ks < 16; ++ks) {
            afr0[ks] = *(const h16x8*)(a0 + ks * 256);
            afr1[ks] = *(const h16x8*)(a1 + ks * 256);
        }
    }

    // units this lane owns (one per tile; all 4 gates in acc regs)
    const int j0 = hg * 64 + mt * 8 + kq;      // tile 0
    const int j1 = j0 + 4;                     // tile 1

    float cst0 = c0[b * HH + j0];
    float cst1 = c0[b * HH + j1];

    for (int t = 0; t < SS; ++t) {
        // XP prefetch (plain cached loads, before the spin)
        u64 xq0 = XPq[((size_t)j0 * SS + t) * BB + b];
        u64 xq1 = XPq[((size_t)j1 * SS + t) * BB + b];

        // spin: lane-parallel poll of the 8 producers of this bg-group
        if (tid < 8) { while (ld_i32_coh(&flags[(bg * 8 + tid) * 16]) < t) {} }
        asm volatile("" ::: "memory");
        __syncthreads();

        // ingest 16 KB slice -> k-major swizzled LDS (4 coalesced u64/thread)
        {
            const u64* src = hb64 + (size_t)(t & 1) * 8192 + bg * 2048;
            u64 v0 = ld_u64_coh(src + 0 * 512 + tid);
            u64 v1 = ld_u64_coh(src + 1 * 512 + tid);
            u64 v2 = ld_u64_coh(src + 2 * 512 + tid);
            u64 v3 = ld_u64_coh(src + 3 * 512 + tid);
            #pragma unroll
            for (int i = 0; i < 4; ++i) {
                u64 v = (i == 0) ? v0 : (i == 1) ? v1 : (i == 2) ? v2 : v3;
                int idx = i * 512 + tid;             // u64 index in slice
                int blr = idx >> 7, k4 = idx & 127;  // src: [b][k4]
                int k8 = k4 >> 1, half = k4 & 1;
                *(u64*)(HLc + (k8 * 16 + (blr ^ (k8 & 7))) * 16 + half * 8) = v;
            }
        }
        __syncthreads();

        // K-loop: 16 wave-linear ds_read_b128 + 32 MFMAs 16x16x32
        f32x4 acc0 = {0.f, 0.f, 0.f, 0.f}, acc1 = {0.f, 0.f, 0.f, 0.f};
        #pragma unroll
        for (int ks = 0; ks < 16; ++ks) {
            const int k8 = ks * 4 + kq;
            h16x8 bf = *(const h16x8*)(HLc + (k8 * 16 + (bl ^ (k8 & 7))) * 16);
            acc0 = __builtin_amdgcn_mfma_f32_16x16x32_f16(afr0[ks], bf, acc0, 0, 0, 0);
            acc1 = __builtin_amdgcn_mfma_f32_16x16x32_f16(afr1[ks], bf, acc1, 0, 0, 0);
        }

        // in-register pointwise (acc reg index == gate)
        float hv0, hv1;
        {
            union { u64 u; u16 s[4]; } xu; xu.u = xq0;
            float af = acc0[0] + h2f(xu.s[0]);
            float ai = acc0[1] + h2f(xu.s[1]);
            float ac = acc0[2] + h2f(xu.s[2]);
            float ao = acc0[3] + h2f(xu.s[3]);
            float cn = cst0 * sigf(af) + sigf(ai) * tanhf_(ac);
            cst0 = cn; hv0 = sigf(ao) * tanhf_(cn);
        }
        {
            union { u64 u; u16 s[4]; } xu; xu.u = xq1;
            float af = acc1[0] + h2f(xu.s[0]);
            float ai = acc1[1] + h2f(xu.s[1]);
            float ac = acc1[2] + h2f(xu.s[2]);
            float ao = acc1[3] + h2f(xu.s[3]);
            float cn = cst1 * sigf(af) + sigf(ai) * tanhf_(ac);
            cst1 = cn; hv1 = sigf(ao) * tanhf_(cn);
        }
        // hst swizzled (bits 3-5 of jl XOR bl&7): conflict-light u16 writes
        hst[bl * 64 + ((mt * 8 + kq)     ^ ((bl & 7) << 3))] = f2h(hv0);
        hst[bl * 64 + ((mt * 8 + 4 + kq) ^ ((bl & 7) << 3))] = f2h(hv1);

        if (t < SS - 1) {
            __syncthreads();   // hst complete
            if (tid < 256) {
                int blr = tid >> 4, ju = tid & 15;
                // inverse swizzle: u64 row idx = ((ju>>1)^(blr&7))*2 | (ju&1)
                int sj = ((((ju >> 1) ^ (blr & 7)) << 1) | (ju & 1));
                st_u64_coh(hb64 + (size_t)((t + 1) & 1) * 8192 + bg * 2048
                               + blr * 128 + hg * 16 + ju,
                           hst64[blr * 16 + sj]);
            }
            __syncthreads();   // vmcnt(0) drain -> stores visible at L3
            if (tid == 0) st_i32_coh(&flags[(bg * 8 + hg) * 16], t + 1);
        }

        // out stores after flag publish (drain hides in next step)
        out[((size_t)t * BB + b) * HH + j0] = hv0;
        out[((size_t)t * BB + b) * HH + j1] = hv1;
        if (t == SS - 1) {
            out[(size_t)SS * BB * HH + b * HH + j0] = hv0;
            out[(size_t)SS * BB * HH + b * HH + j1] = hv1;
            out[(size_t)SS * BB * HH + BB * HH + b * HH + j0] = cst0;
            out[(size_t)SS * BB * HH + BB * HH + b * HH + j1] = cst1;
        }
    }
}

// ===================================================================
// R5 fallback path (proven 2.63 ms) — verbatim
// ===================================================================
__global__ __launch_bounds__(256) void prep_A(
    const float* __restrict__ Wfi, const float* __restrict__ Wfh,
    const float* __restrict__ Wii, const float* __restrict__ Wih,
    const float* __restrict__ Wci, const float* __restrict__ Wch,
    const float* __restrict__ Woi, const float* __restrict__ Woh,
    u32* __restrict__ A)
{
    int tid = blockIdx.x * 256 + threadIdx.x;
    int wg = tid / 24576;  int r = tid - wg * 24576;
    int mt = r / 12288;    r -= mt * 12288;
    int ks = r / 6144;     r -= ks * 6144;
    int kt = r / 256;      r -= kt * 256;
    int l  = r >> 2;       int d = r & 3;

    int row = mt * 32 + (l & 31);
    int g   = row >> 4;
    int j   = wg * 16 + (row & 15);
    int k   = ks * 384 + kt * 16 + (l >> 5) * 8 + d * 2;

    const float* Wi = (g == 0) ? Wfi : (g == 1) ? Wii : (g == 2) ? Wci : Woi;
    const float* Wh = (g == 0) ? Wfh : (g == 1) ? Wih : (g == 2) ? Wch : Woh;
    float w0, w1;
    if (k < II) { w0 = Wi[j * II + k];        w1 = Wi[j * II + k + 1]; }
    else        { int kk = k - II; w0 = Wh[j * HH + kk]; w1 = Wh[j * HH + kk + 1]; }
    A[tid] = pk2h(w0, w1);
}

__global__ __launch_bounds__(256) void prep_misc(
    const float* __restrict__ h0, u16* __restrict__ hb, int* __restrict__ flags)
{
    int tid = blockIdx.x * 256 + threadIdx.x;
    if (tid < BB * HH) {
        int b = tid >> 9, j = tid & 511;
        hb[(j >> 3) * 512 + b * 8 + (j & 7)] = f2h(h0[tid]);
    }
    if (tid < 32) flags[tid * 32] = 0;
}

__global__ __launch_bounds__(512, 1) void lstm_mfma(
    const float* __restrict__ x,  const float* __restrict__ c0,
    const float* __restrict__ bfi, const float* __restrict__ bfh,
    const float* __restrict__ bii, const float* __restrict__ bih,
    const float* __restrict__ bci, const float* __restrict__ bch,
    const float* __restrict__ boi, const float* __restrict__ boh,
    const u32* __restrict__ A, u16* __restrict__ hb, int* __restrict__ flags,
    float* __restrict__ out)
{
    const int wg   = blockIdx.x;
    const int tid  = threadIdx.x;
    const int lane = tid & 63;
    const int w    = tid >> 6;
    const int mt   = w & 1;
    const int nt2  = (w >> 1) & 1;
    const int ks   = w >> 2;
    const int khi  = lane >> 5;
    const int nb   = nt2 * 32 + (lane & 31);

    __shared__ __align__(16) u16 BS[8192 * 8];
    char* BSc = (char*)BS;

    h16x8 afr[24];
    {
        const u32* ab = A + ((wg * 2 + mt) * 2 + ks) * (24 * 256) + lane * 4;
        #pragma unroll
        for (int kt = 0; kt < 24; ++kt)
            afr[kt] = *(const h16x8*)(ab + kt * 256);
    }

    f32x16 acc_init;
    #pragma unroll
    for (int rg = 0; rg < 16; ++rg) {
        int row = mt * 32 + (rg & 3) + 8 * (rg >> 2) + 4 * khi;
        float bv = 0.0f;
        if (ks == 0) {
            int g = row >> 4, j = wg * 16 + (row & 15);
            const float* bi = (g == 0) ? bfi : (g == 1) ? bii : (g == 2) ? bci : boi;
            const float* bh = (g == 0) ? bfh : (g == 1) ? bih : (g == 2) ? bch : boh;
            bv = bi[j] + bh[j];
        }
        acc_init[rg] = bv;
    }

    const int bown = tid & 63;
    const int w8   = tid >> 6;
    const int j0   = wg * 16 + 2 * w8;
    float cst[2];
    {
        const f32x2 cv = *(const f32x2*)(c0 + bown * HH + j0);
        cst[0] = cv.x; cst[1] = cv.y;
    }

    #pragma unroll
    for (int i = 0; i < 4; ++i) {
        int cid = i * 512 + tid;
        int bq = cid >> 5, k8 = cid & 31;
        const f32x4* sp = (const f32x4*)(x + bq * II + k8 * 8);
        f32x4 v0 = sp[0], v1 = sp[1];
        u32x4 pk;
        pk.x = pk2h(v0[0], v0[1]); pk.y = pk2h(v0[2], v0[3]);
        pk.z = pk2h(v1[0], v1[1]); pk.w = pk2h(v1[2], v1[3]);
        *(u32x4*)&BSc[(k8 * 64 + (bq ^ (k8 & 7))) * 16] = pk;
    }

    for (int t = 0; t < SS; ++t) {
        const int cur = t & 1;
        float* GLp = (float*)(BSc + (size_t)(cur ^ 1) * 2048 * 16);

        {
            const u16* hsrc = hb + cur * (BB * HH);
            u64 hr[16];
            #pragma unroll
            for (int it = 0; it < 8; ++it) {
                int cd = it * 512 + tid;
                int k8h = cd >> 6, bpos = cd & 63;
                int bq = bpos ^ (k8h & 7);
                const u64* p = (const u64*)(hsrc + k8h * 512 + bq * 8);
                hr[2 * it]     = ld_u64_coh(p);
                hr[2 * it + 1] = ld_u64_coh(p + 1);
            }
            #pragma unroll
            for (int it = 0; it < 8; ++it) {
                int cd = it * 512 + tid;
                union { u64 q[2]; u32x4 v; } u;
                u.q[0] = hr[2 * it]; u.q[1] = hr[2 * it + 1];
                *(u32x4*)&BSc[(4096 + cd) * 16] = u.v;
            }
        }

        f32x4 xv[8];
        if (t + 1 < SS) {
            const float* xt = x + (size_t)(t + 1) * BB * II;
            #pragma unroll
            for (int i = 0; i < 4; ++i) {
                int cid = i * 512 + tid;
                int bq = cid >> 5, k8 = cid & 31;
                const f32x4* sp = (const f32x4*)(xt + bq * II + k8 * 8);
                xv[2 * i] = sp[0]; xv[2 * i + 1] = sp[1];
            }
        }

        __syncthreads();

        f32x16 acc = acc_init;
        #pragma unroll
        for (int kt = 0; kt < 24; ++kt) {
            int k8g = ks * 48 + kt * 2 + khi;
            int off;
            if (k8g < 32) { int q = k8g & 7;
                off = (cur * 2048 + k8g * 64 + ((nb ^ q))) * 16;
            } else {        int k8h = k8g - 32; int q = k8h & 7;
                off = (4096 + k8h * 64 + ((nb ^ q))) * 16;
            }
            h16x8 bf = *(const h16x8*)(BSc + off);
            acc = __builtin_amdgcn_mfma_f32_32x32x16_f16(afr[kt], bf, acc, 0, 0, 0);
        }

        #pragma unroll
        for (int rg = 0; rg < 16; ++rg) {
            int row = mt * 32 + (rg & 3) + 8 * (rg >> 2) + 4 * khi;
            GLp[ks * 4096 + row * 64 + nb] = acc[rg];
        }
        __syncthreads();

        float hv2[2];
        #pragma unroll
        for (int i = 0; i < 2; ++i) {
            int m = 2 * w8 + i;
            float af = GLp[(0 * 16 + m) * 64 + bown] + GLp[4096 + (0 * 16 + m) * 64 + bown];
            float ai = GLp[(1 * 16 + m) * 64 + bown] + GLp[4096 + (1 * 16 + m) * 64 + bown];
            float ac = GLp[(2 * 16 + m) * 64 + bown] + GLp[4096 + (2 * 16 + m) * 64 + bown];
            float ao = GLp[(3 * 16 + m) * 64 + bown] + GLp[4096 + (3 * 16 + m) * 64 + bown];
            float fg = sigf(af), ig = sigf(ai), cg = tanhf_(ac), og = sigf(ao);
            float cn = cst[i] * fg + ig * cg;
            cst[i] = cn;
            hv2[i] = og * tanhf_(cn);
        }
        {
            f32x2 ho; ho.x = hv2[0]; ho.y = hv2[1];
            *(f32x2*)(out + ((size_t)t * BB + bown) * HH + j0) = ho;
        }
        st_u32_coh((u32*)(hb + ((t + 1) & 1) * (BB * HH) + (j0 >> 3) * 512 + bown * 8 + (j0 & 7)),
                   pk2h(hv2[0], hv2[1]));

        if (t == SS - 1) {
            f32x2 ho; ho.x = hv2[0]; ho.y = hv2[1];
            f32x2 co; co.x = cst[0]; co.y = cst[1];
            *(f32x2*)(out + (size_t)SS * BB * HH + bown * HH + j0) = ho;
            *(f32x2*)(out + (size_t)SS * BB * HH + BB * HH + bown * HH + j0) = co;
            break;
        }

        __syncthreads();
        if (tid == 0) st_i32_coh(&flags[wg * 32], t + 1);

        #pragma unroll
        for (int i = 0; i < 4; ++i) {
            int cid = i * 512 + tid;
            int bq = cid >> 5, k8 = cid & 31;
            f32x4 v0 = xv[2 * i], v1 = xv[2 * i + 1];
            u32x4 pk;
            pk.x = pk2h(v0[0], v0[1]); pk.y = pk2h(v0[2], v0[3]);
            pk.z = pk2h(v1[0], v1[1]); pk.w = pk2h(v1[2], v1[3]);
            *(u32x4*)&BSc[((cur ^ 1) * 2048 + k8 * 64 + (bq ^ (k8 & 7))) * 16] = pk;
        }

        if (tid < 32) {
            while (ld_i32_coh(&flags[tid * 32]) < t + 1) {}
        }
        asm volatile("" ::: "memory");
        __syncthreads();
    }
}

extern "C" void kernel_launch(void* const* d_in, const int* in_sizes, int n_in,
                              void* d_out, int out_size, void* d_ws, size_t ws_size,
                              hipStream_t stream) {
    const float* x   = (const float*)d_in[0];
    const float* h0  = (const float*)d_in[1];
    const float* c0  = (const float*)d_in[2];
    const float* Wfi = (const float*)d_in[3];
    const float* bfi = (const float*)d_in[4];
    const float* Wfh = (const float*)d_in[5];
    const float* bfh = (const float*)d_in[6];
    const float* Wii = (const float*)d_in[7];
    const float* bii = (const float*)d_in[8];
    const float* Wih = (const float*)d_in[9];
    const float* bih = (const float*)d_in[10];
    const float* Wci = (const float*)d_in[11];
    const float* bci = (const float*)d_in[12];
    const float* Wch = (const float*)d_in[13];
    const float* bch = (const float*)d_in[14];
    const float* Woi = (const float*)d_in[15];
    const float* boi = (const float*)d_in[16];
    const float* Woh = (const float*)d_in[17];
    const float* boh = (const float*)d_in[18];

    if (ws_size >= WS_XP) {
        u32*   A2   = (u32*)((char*)d_ws + XA2_OFF);
        u32*   WXA  = (u32*)((char*)d_ws + XWXA_OFF);
        float* bsum = (float*)((char*)d_ws + XBS_OFF);
        u16*   hbb  = (u16*)((char*)d_ws + XHB_OFF);
        int*   flg  = (int*)((char*)d_ws + XFL_OFF);
        u64*   XPq  = (u64*)((char*)d_ws + XXP_OFF);

        xprep_pack<<<dim3((A2_DW + WXA_DW + GROW + 255) / 256), dim3(256), 0, stream>>>(
            Wfi, Wfh, Wii, Wih, Wci, Wch, Woi, Woh,
            bfi, bfh, bii, bih, bci, bch, boi, boh, A2, WXA, bsum);
        xprep_hb<<<dim3(128), dim3(256), 0, stream>>>(h0, hbb, flg);
        xproj<<<dim3(TBN / 128), dim3(512), 0, stream>>>(x, WXA, bsum, XPq);
        lstm_rec<<<dim3(NWG), dim3(512), 0, stream>>>(c0, A2, hbb, flg, XPq, (float*)d_out);
    } else {
        u32* A     = (u32*)d_ws;
        u16* hbb   = (u16*)((char*)d_ws + HB_OFF);
        int* flags = (int*)((char*)d_ws + FL_OFF);
        prep_A<<<dim3(A_DWORDS / 256), dim3(256), 0, stream>>>(
            Wfi, Wfh, Wii, Wih, Wci, Wch, Woi, Woh, A);
        prep_misc<<<dim3(128), dim3(256), 0, stream>>>(h0, hbb, flags);
        lstm_mfma<<<dim3(32), dim3(512), 0, stream>>>(
            x, c0, bfi, bfh, bii, bih, bci, bch, boi, boh,
            A, hbb, flags, (float*)d_out);
    }
}